// Round 6
// baseline (342.542 us; speedup 1.0000x reference)
//
#include <hip/hip_runtime.h>

#define N_GENE 4762
#define N_CELL 847
#define NEDGE  200000
#define D      256
#define NBLK   240          // < 256 CUs -> co-residency guaranteed
#define NTHR   512
#define NT     (NBLK * NTHR)

typedef __attribute__((ext_vector_type(8))) short short8;            // 8 bf16
typedef __attribute__((ext_vector_type(8))) unsigned short ushort8v; // 16B load
typedef __attribute__((ext_vector_type(4))) float f32x4;

// ---- degree segment layout ----
#define S_G_OUT 0
#define S_C_IN  (S_G_OUT + N_GENE)
#define S_C_OUT (S_C_IN + N_CELL)
#define S_G_IN  (S_C_OUT + N_CELL)
#define NBINS   (S_G_IN + N_GENE)      // 11218

#define ALIGN8(x) (((x) + 7) & ~7)

// ---- workspace layout (4-byte slots) ----
#define A_DEG     0                           // int[11218]
#define A_NRM     (A_DEG + NBINS)             // float[11218]
#define A_OFFS_C  (A_NRM + NBINS)             // int[848]
#define A_OFFS_G  (A_OFFS_C + N_CELL + 1)     // int[4763]
#define A_CUR_C   (A_OFFS_G + N_GENE + 1)     // int[847]
#define A_CUR_G   (A_CUR_C + N_CELL)          // int[4762]
#define A_CTR     ALIGN8(A_CUR_G + N_GENE)    // int[8]
#define A_SG      (A_CTR + 8)                 // float[4762]
#define A_SC      (A_SG + N_GENE)             // float[847]
#define A_SORT_C  ALIGN8(A_SC + N_CELL)       // int2[200000]
#define A_SORT_G  (A_SORT_C + 2 * NEDGE)      // int2[200000]
#define A_GENE_BF ALIGN8(A_SORT_G + 2 * NEDGE)
#define A_CELL_BF ALIGN8(A_GENE_BF + N_GENE * D / 2)
#define A_WT1_BF  ALIGN8(A_CELL_BF + N_CELL * D / 2)
#define A_WT2_BF  ALIGN8(A_WT1_BF + D * D / 2)
#define A_AGGC_BF ALIGN8(A_WT2_BF + D * D / 2)
#define A_AGGG_BF ALIGN8(A_AGGC_BF + N_CELL * D / 2)

__device__ __forceinline__ unsigned short f2bf(float f) {
    unsigned u = __float_as_uint(f);
    u = (u + 0x7FFFu + ((u >> 16) & 1u)) >> 16;    // RNE
    return (unsigned short)u;
}
__device__ __forceinline__ float bf2f(unsigned short b) {
    return __uint_as_float(((unsigned)b) << 16);
}

// Grid barrier, relaxed-poll variant: ONE release-RMW on arrival, RELAXED
// polls (no per-iteration cache invalidation), one acquire-RMW on exit.
// Timeout-hardened: breaks out (graceful wrong answer) instead of hanging.
__device__ __forceinline__ void gbar(int* ctr, int target) {
    __syncthreads();
    if (threadIdx.x == 0) {
        __hip_atomic_fetch_add(ctr, 1, __ATOMIC_RELEASE, __HIP_MEMORY_SCOPE_AGENT);
        long long t0 = (long long)__builtin_amdgcn_s_memrealtime();
        while (__hip_atomic_load(ctr, __ATOMIC_RELAXED, __HIP_MEMORY_SCOPE_AGENT) < target) {
            __builtin_amdgcn_s_sleep(8);
            if ((long long)__builtin_amdgcn_s_memrealtime() - t0 > 50000000LL) break;
        }
        __hip_atomic_fetch_add(ctr, 0, __ATOMIC_ACQUIRE, __HIP_MEMORY_SCOPE_AGENT);
    }
    __syncthreads();
}

// Zero barrier counters + deg (workspace is poisoned between runs).
__global__ __launch_bounds__(256) void k_zero(int* __restrict__ deg, int* __restrict__ ctrs) {
    int gid = blockIdx.x * 256 + threadIdx.x;
    for (int i = gid; i < NBINS; i += 16 * 256) deg[i] = 0;
    if (gid < 8) ctrs[gid] = 0;
}

// One fused kernel, 6 phases, 5 relaxed-poll grid barriers.
__global__ __launch_bounds__(NTHR, 2) void k_all(
        const int* __restrict__ g2c_src, const int* __restrict__ g2c_dst,
        const int* __restrict__ c2g_src, const int* __restrict__ c2g_dst,
        const int* __restrict__ dec_src, const int* __restrict__ dec_dst,
        const float* __restrict__ gene_emb, const float* __restrict__ cell_emb,
        const float* __restrict__ W_g2c, const float* __restrict__ W_c2g,
        const float* __restrict__ b_g2c, const float* __restrict__ b_c2g,
        const float* __restrict__ Wp, const float* __restrict__ bp,
        int* __restrict__ deg, float* __restrict__ nrm,
        int* __restrict__ offsC, int* __restrict__ offsG,
        int* __restrict__ curC, int* __restrict__ curG,
        float* __restrict__ sg, float* __restrict__ sc,
        int2* __restrict__ sortC, int2* __restrict__ sortG,
        unsigned short* __restrict__ gene_bf, unsigned short* __restrict__ cell_bf,
        unsigned short* __restrict__ wt1, unsigned short* __restrict__ wt2,
        unsigned short* __restrict__ aggC, unsigned short* __restrict__ aggG,
        float* __restrict__ hC, float* __restrict__ hG,
        float* __restrict__ out_score,
        int* __restrict__ ctrs) {
    __shared__ int   sidx[8][64];
    __shared__ float snrm[8][64];
    __shared__ float pacc[8][256];
    __shared__ int   wsum[8];
    int gid = blockIdx.x * NTHR + threadIdx.x;
    int T = threadIdx.x;
    int w = T >> 6, lane = T & 63;

    // ---------------- P0: bf16 cvt + W transpose + degree hist ----------------
    {
        const int NG = N_GENE * D, NC = N_CELL * D, NW = D * D;
        const int total = NG + NC + 2 * NW;
        for (int i = gid; i < total; i += NT) {
            if (i < NG) {
                gene_bf[i] = f2bf(gene_emb[i]);
            } else if (i < NG + NC) {
                int j = i - NG;
                cell_bf[j] = f2bf(cell_emb[j]);
            } else if (i < NG + NC + NW) {
                int j = i - NG - NC;
                wt1[j] = f2bf(W_g2c[(j & 255) * D + (j >> 8)]);
            } else {
                int j = i - NG - NC - NW;
                wt2[j] = f2bf(W_c2g[(j & 255) * D + (j >> 8)]);
            }
        }
        for (int e = gid; e < NEDGE; e += NT) {
            atomicAdd(&deg[S_G_OUT + g2c_src[e]], 1);
            atomicAdd(&deg[S_C_IN  + g2c_dst[e]], 1);
            atomicAdd(&deg[S_C_OUT + c2g_src[e]], 1);
            atomicAdd(&deg[S_G_IN  + c2g_dst[e]], 1);
        }
    }
    gbar(&ctrs[0], NBLK);

    // ---------------- P1: offset scans (blocks 0,1) + nrm (rest) ----------------
    if (blockIdx.x < 2) {
        int dir = blockIdx.x;
        const int* dgs = dir ? deg + S_G_IN : deg + S_C_IN;
        int nb         = dir ? N_GENE : N_CELL;
        int* goffs     = dir ? offsG : offsC;
        int* gcur      = dir ? curG : curC;
        int per = (nb + NTHR - 1) / NTHR;           // <=10
        int i0 = T * per, i1 = min(nb, i0 + per);
        int loc[10];
        int s = 0;
        for (int i = i0; i < i1; i++) { loc[i - i0] = s; s += dgs[i]; }
        int t = s;
        #pragma unroll
        for (int off = 1; off < 64; off <<= 1) {
            int u = __shfl_up(t, off);
            if (lane >= off) t += u;
        }
        if (lane == 63) wsum[w] = t;
        __syncthreads();
        if (w == 0 && lane < 8) {
            int x = wsum[lane];
            #pragma unroll
            for (int off = 1; off < 8; off <<= 1) {
                int u = __shfl_up(x, off);
                if (lane >= off) x += u;
            }
            wsum[lane] = x;
        }
        __syncthreads();
        int wbase = w ? wsum[w - 1] : 0;
        int excl = wbase + t - s;
        for (int i = i0; i < i1; i++) {
            int v = excl + loc[i - i0];
            goffs[i] = v;
            gcur[i] = v;
        }
        if (T == NTHR - 1) goffs[nb] = excl + s;
    } else {
        for (int j = (blockIdx.x - 2) * NTHR + T; j < NBINS; j += (NBLK - 2) * NTHR)
            nrm[j] = rsqrtf(fmaxf((float)deg[j], 1.0f));
    }
    gbar(&ctrs[1], NBLK);

    // ---------------- P2: scatter via global cursors ----------------
    for (int t2 = gid; t2 < 2 * NEDGE; t2 += NT) {
        int dir = t2 >= NEDGE;
        int e = dir ? t2 - NEDGE : t2;
        const int* srcp = dir ? c2g_src : g2c_src;
        const int* dstp = dir ? c2g_dst : g2c_dst;
        int sseg        = dir ? S_C_OUT : S_G_OUT;
        int* cur        = dir ? curG : curC;
        int2* sorted    = dir ? sortG : sortC;
        int d = dstp[e], sv = srcp[e];
        float nv = nrm[sseg + sv];
        int pos = atomicAdd(&cur[d], 1);
        sorted[pos] = make_int2(sv, __float_as_int(nv));
    }
    gbar(&ctrs[2], NBLK);

    // ---------------- P3: aggregation (grid-strided units) ----------------
    {
        const int NCU = N_CELL;
        const int NGU = (N_GENE + 7) >> 3;
        int half = lane >> 5, li = lane & 31;
        for (int u = blockIdx.x; u < NCU + NGU; u += NBLK) {
            bool isCell = u < NCU;
            int e0, e1, node;
            const unsigned short* emb;
            const int2* sorted;
            if (isCell) {
                node = u;
                int f0 = offsC[node], f1 = offsC[node + 1];
                int ne = f1 - f0, nw8 = (ne + 7) >> 3;
                e0 = f0 + w * nw8; e1 = min(f1, e0 + nw8);
                emb = gene_bf; sorted = sortC;
            } else {
                node = (u - NCU) * 8 + w;
                if (node < N_GENE) { e0 = offsG[node]; e1 = offsG[node + 1]; }
                else { e0 = 0; e1 = 0; }
                emb = cell_bf; sorted = sortG;
            }
            float acc[8];
            #pragma unroll
            for (int c = 0; c < 8; c++) acc[c] = 0.f;

            for (int base = e0; base < e1; base += 64) {
                int n = min(64, e1 - base);
                if (lane < n) {
                    int2 pr = sorted[base + lane];
                    sidx[w][lane] = pr.x;
                    snrm[w][lane] = __int_as_float(pr.y);
                }
                int i = 0;
                for (; 2 * i + 16 <= n; i += 8) {
                    ushort8v v[8];
                    float nv[8];
                    #pragma unroll
                    for (int k = 0; k < 8; k++) {
                        int jj = 2 * i + 2 * k + half;
                        v[k] = *(const ushort8v*)&emb[sidx[w][jj] * D + li * 8];
                        nv[k] = snrm[w][jj];
                    }
                    #pragma unroll
                    for (int c = 0; c < 8; c++) {
                        float s0 = 0.f;
                        #pragma unroll
                        for (int k = 0; k < 8; k++) s0 += bf2f(v[k][c]) * nv[k];
                        acc[c] += s0;
                    }
                }
                for (; 2 * i + 8 <= n; i += 4) {
                    int j0 = 2 * i + half, j1 = 2 * i + 2 + half;
                    int j2 = 2 * i + 4 + half, j3 = 2 * i + 6 + half;
                    ushort8v v0 = *(const ushort8v*)&emb[sidx[w][j0] * D + li * 8];
                    ushort8v v1 = *(const ushort8v*)&emb[sidx[w][j1] * D + li * 8];
                    ushort8v v2 = *(const ushort8v*)&emb[sidx[w][j2] * D + li * 8];
                    ushort8v v3 = *(const ushort8v*)&emb[sidx[w][j3] * D + li * 8];
                    float n0 = snrm[w][j0], n1 = snrm[w][j1];
                    float n2 = snrm[w][j2], n3 = snrm[w][j3];
                    #pragma unroll
                    for (int c = 0; c < 8; c++)
                        acc[c] += bf2f(v0[c]) * n0 + bf2f(v1[c]) * n1 +
                                  bf2f(v2[c]) * n2 + bf2f(v3[c]) * n3;
                }
                int npair = (n + 1) >> 1;
                for (; i < npair; i++) {
                    int jj = 2 * i + half;
                    bool ok = jj < n;
                    int idx = ok ? sidx[w][jj] : sidx[w][0];
                    float nv = ok ? snrm[w][jj] : 0.f;
                    ushort8v v = *(const ushort8v*)&emb[idx * D + li * 8];
                    #pragma unroll
                    for (int c = 0; c < 8; c++) acc[c] += bf2f(v[c]) * nv;
                }
            }
            #pragma unroll
            for (int c = 0; c < 8; c++) acc[c] += __shfl_xor(acc[c], 32);

            if (isCell) {
                if (half == 0) {
                    #pragma unroll
                    for (int c = 0; c < 8; c++) pacc[w][li * 8 + c] = acc[c];
                }
                __syncthreads();
                if (T < 256) {
                    float s2 = 0.f;
                    #pragma unroll
                    for (int w8 = 0; w8 < 8; w8++) s2 += pacc[w8][T];
                    aggC[node * D + T] = f2bf(s2 * nrm[S_C_IN + node]);
                }
                __syncthreads();
            } else {
                if (node < N_GENE && half == 0) {
                    float ndv = nrm[S_G_IN + node];
                    ushort8v o;
                    #pragma unroll
                    for (int c = 0; c < 8; c++) o[c] = f2bf(acc[c] * ndv);
                    *(ushort8v*)&aggG[node * D + li * 8] = o;
                }
            }
        }
    }
    gbar(&ctrs[3], NBLK);

    // ---------------- P4: MFMA GEMMs + bias + relu + Wp row-dots ----------------
    {
        const int CT = (N_CELL + 15) / 16;   // 53
        const int GT = (N_GENE + 15) / 16;   // 298
        int wid = blockIdx.x * 8 + w;
        if (wid < CT + GT) {
            bool isCell = wid < CT;
            int tile = isCell ? wid : wid - CT;
            int m0 = tile * 16;
            int M = isCell ? N_CELL : N_GENE;
            const unsigned short* A  = isCell ? aggC : aggG;
            const unsigned short* Wt = isCell ? wt1 : wt2;
            const float* bias = isCell ? b_g2c : b_c2g;
            const float* wp   = isCell ? Wp + D : Wp;
            float* H  = isCell ? hC : hG;
            float* sv = isCell ? sc : sg;
            int l15 = lane & 15, quad = lane >> 4;
            int arow = m0 + l15;
            if (arow >= M) arow = M - 1;
            f32x4 acc[16];
            #pragma unroll
            for (int t = 0; t < 16; t++) acc[t] = (f32x4){0.f, 0.f, 0.f, 0.f};
            #pragma unroll
            for (int k0 = 0; k0 < D; k0 += 32) {
                short8 a = *(const short8*)&A[arow * D + k0 + quad * 8];
                #pragma unroll
                for (int t = 0; t < 16; t++) {
                    short8 b = *(const short8*)&Wt[(t * 16 + l15) * D + k0 + quad * 8];
                    acc[t] = __builtin_amdgcn_mfma_f32_16x16x32_bf16(a, b, acc[t], 0, 0, 0);
                }
            }
            float dot[4] = {0.f, 0.f, 0.f, 0.f};
            #pragma unroll
            for (int t = 0; t < 16; t++) {
                int col = t * 16 + l15;
                float bv = bias[col], wv = wp[col];
                #pragma unroll
                for (int r = 0; r < 4; r++) {
                    int row = m0 + quad * 4 + r;
                    float h = fmaxf(acc[t][r] + bv, 0.f);
                    if (row < M) H[row * D + col] = h;
                    dot[r] += h * wv;
                }
            }
            #pragma unroll
            for (int off = 1; off < 16; off <<= 1) {
                #pragma unroll
                for (int r = 0; r < 4; r++) dot[r] += __shfl_xor(dot[r], off);
            }
            if (l15 == 0) {
                #pragma unroll
                for (int r = 0; r < 4; r++) {
                    int row = m0 + quad * 4 + r;
                    if (row < M) sv[row] = dot[r];
                }
            }
        }
    }
    gbar(&ctrs[4], NBLK);

    // ---------------- P5: edge scores ----------------
    {
        float bpv = bp[0];
        for (int i = gid; i < NEDGE; i += NT)
            out_score[i] = sg[dec_src[i]] + sc[dec_dst[i]] + bpv;
    }
}

extern "C" void kernel_launch(void* const* d_in, const int* in_sizes, int n_in,
                              void* d_out, int out_size, void* d_ws, size_t ws_size,
                              hipStream_t stream) {
    const float* gene_emb = (const float*)d_in[0];
    const float* cell_emb = (const float*)d_in[1];
    const float* W_g2c    = (const float*)d_in[2];
    const float* b_g2c    = (const float*)d_in[3];
    const float* W_c2g    = (const float*)d_in[4];
    const float* b_c2g    = (const float*)d_in[5];
    const float* Wp       = (const float*)d_in[6];
    const float* bp       = (const float*)d_in[7];
    const int* g2c_src = (const int*)d_in[8];
    const int* g2c_dst = (const int*)d_in[9];
    const int* c2g_src = (const int*)d_in[10];
    const int* c2g_dst = (const int*)d_in[11];
    const int* dec_src = (const int*)d_in[12];
    const int* dec_dst = (const int*)d_in[13];

    int*   wsi = (int*)d_ws;
    float* wsf = (float*)d_ws;
    unsigned short* gene_bf = (unsigned short*)(wsi + A_GENE_BF);
    unsigned short* cell_bf = (unsigned short*)(wsi + A_CELL_BF);
    unsigned short* wt1     = (unsigned short*)(wsi + A_WT1_BF);
    unsigned short* wt2     = (unsigned short*)(wsi + A_WT2_BF);
    unsigned short* aggC    = (unsigned short*)(wsi + A_AGGC_BF);
    unsigned short* aggG    = (unsigned short*)(wsi + A_AGGG_BF);
    int2* sortC = (int2*)(wsi + A_SORT_C);
    int2* sortG = (int2*)(wsi + A_SORT_G);

    float* out = (float*)d_out;
    float* out_score = out;                      // [200000]
    float* out_hgene = out + NEDGE;              // [4762*256]
    float* out_hcell = out + NEDGE + N_GENE * D; // [847*256]

    // 1. zero deg + barrier counters (ws poisoned between runs)
    k_zero<<<16, 256, 0, stream>>>(wsi + A_DEG, wsi + A_CTR);
    // 2. everything else in one fused kernel (5 relaxed-poll grid barriers)
    k_all<<<NBLK, NTHR, 0, stream>>>(
        g2c_src, g2c_dst, c2g_src, c2g_dst, dec_src, dec_dst,
        gene_emb, cell_emb, W_g2c, W_c2g, b_g2c, b_c2g, Wp, bp,
        wsi + A_DEG, wsf + A_NRM,
        wsi + A_OFFS_C, wsi + A_OFFS_G, wsi + A_CUR_C, wsi + A_CUR_G,
        wsf + A_SG, wsf + A_SC, sortC, sortG,
        gene_bf, cell_bf, wt1, wt2, aggC, aggG,
        out_hcell, out_hgene, out_score, wsi + A_CTR);
}

// Round 7
// 140.755 us; speedup vs baseline: 2.4336x; 2.4336x over previous
//
#include <hip/hip_runtime.h>

#define N_GENE 4762
#define N_CELL 847
#define NEDGE  200000
#define D      256
#define NPART  64     // hist/scatter chunks

typedef __attribute__((ext_vector_type(8))) short short8;            // 8 bf16
typedef __attribute__((ext_vector_type(8))) unsigned short ushort8v; // 16B load
typedef __attribute__((ext_vector_type(4))) float f32x4;

// ---- histogram segment layout (bins, concatenated) ----
#define S_G_OUT 0                      // [4762] g2c_src degrees (genes)
#define S_C_IN  (S_G_OUT + N_GENE)     // [847]  g2c_dst degrees (cells)
#define S_C_OUT (S_C_IN + N_CELL)      // [847]  c2g_src degrees (cells)
#define S_G_IN  (S_C_OUT + N_CELL)     // [4762] c2g_dst degrees (genes)
#define NBINS   (S_G_IN + N_GENE)      // 11218

#define ALIGN8(x) (((x) + 7) & ~7)

// ---- workspace layout (4-byte slots) ----
#define A_DEG      0                          // int[11218]
#define A_NRM      (A_DEG + NBINS)            // float[11218]
#define A_OFFS_C   (A_NRM + NBINS)            // int[848]
#define A_OFFS_G   (A_OFFS_C + N_CELL + 1)    // int[4763]
#define A_SORT_C   ALIGN8(A_OFFS_G + N_GENE + 1) // int2[200000]
#define A_SORT_G   (A_SORT_C + 2 * NEDGE)     // int2[200000]
#define A_PART     (A_SORT_G + 2 * NEDGE)     // int[64*11218]
#define A_SG       (A_PART + NPART * NBINS)   // float[4762]
#define A_SC       (A_SG + N_GENE)            // float[847]
// bf16 regions (ushort; slot = count/2), 16B-aligned
#define A_GENE_BF  ALIGN8(A_SC + N_CELL)
#define A_CELL_BF  ALIGN8(A_GENE_BF + N_GENE * D / 2)
#define A_WT1_BF   ALIGN8(A_CELL_BF + N_CELL * D / 2)
#define A_WT2_BF   ALIGN8(A_WT1_BF + D * D / 2)
#define A_AGGC_BF  ALIGN8(A_WT2_BF + D * D / 2)
#define A_AGGG_BF  ALIGN8(A_AGGC_BF + N_CELL * D / 2)

__device__ __forceinline__ unsigned short f2bf(float f) {
    unsigned u = __float_as_uint(f);
    u = (u + 0x7FFFu + ((u >> 16) & 1u)) >> 16;    // RNE
    return (unsigned short)u;
}
__device__ __forceinline__ float bf2f(unsigned short b) {
    return __uint_as_float(((unsigned)b) << 16);
}

// blocks 0..255: per-block LDS histograms, 4-way SEGMENT-SPLIT:
//   group s = B>>6 handles one segment (one index array), chunk = B&63.
//   LDS <= 4762 ints; one atomic per edge; partial row (B&63) is assembled
//   by the 4 groups in disjoint segments.
// blocks 256..319: bf16 conversions + W transposes + sg/sc zeroing.
__global__ __launch_bounds__(1024) void k_pre(
        const int* __restrict__ g2c_src, const int* __restrict__ g2c_dst,
        const int* __restrict__ c2g_src, const int* __restrict__ c2g_dst,
        const float* __restrict__ gene_emb, const float* __restrict__ cell_emb,
        const float* __restrict__ W_g2c, const float* __restrict__ W_c2g,
        int* __restrict__ partial,
        unsigned short* __restrict__ gene_bf, unsigned short* __restrict__ cell_bf,
        unsigned short* __restrict__ wt1, unsigned short* __restrict__ wt2,
        float* __restrict__ sg, float* __restrict__ sc) {
    __shared__ int sh[N_GENE];          // max segment size
    int B = blockIdx.x, T = threadIdx.x;
    if (B < 4 * NPART) {
        int grp = B >> 6, blk = B & (NPART - 1);
        const int* idx;
        int segbase, segn;
        if      (grp == 0) { idx = g2c_src; segbase = S_G_OUT; segn = N_GENE; }
        else if (grp == 1) { idx = g2c_dst; segbase = S_C_IN;  segn = N_CELL; }
        else if (grp == 2) { idx = c2g_src; segbase = S_C_OUT; segn = N_CELL; }
        else               { idx = c2g_dst; segbase = S_G_IN;  segn = N_GENE; }
        for (int j = T; j < segn; j += 1024) sh[j] = 0;
        __syncthreads();
        const int chunk = (NEDGE + NPART - 1) / NPART;
        int e0 = blk * chunk, e1 = min(NEDGE, e0 + chunk);
        for (int e = e0 + T; e < e1; e += 1024) atomicAdd(&sh[idx[e]], 1);
        __syncthreads();
        int* pp = partial + blk * NBINS + segbase;
        for (int j = T; j < segn; j += 1024) pp[j] = sh[j];
    } else {
        const int NG = N_GENE * D, NC = N_CELL * D, NW = D * D;
        const int total = NG + NC + 2 * NW;
        for (int i = (B - 4 * NPART) * 1024 + T; i < total; i += 64 * 1024) {
            if (i < NG) {
                gene_bf[i] = f2bf(gene_emb[i]);
            } else if (i < NG + NC) {
                int j = i - NG;
                cell_bf[j] = f2bf(cell_emb[j]);
            } else if (i < NG + NC + NW) {
                int j = i - NG - NC;
                wt1[j] = f2bf(W_g2c[(j & 255) * D + (j >> 8)]);
            } else {
                int j = i - NG - NC - NW;
                wt2[j] = f2bf(W_c2g[(j & 255) * D + (j >> 8)]);
            }
        }
        // zero sg/sc for k_gemm2's atomic partial dots
        for (int i = (B - 4 * NPART) * 1024 + T; i < N_GENE + N_CELL; i += 64 * 1024) {
            if (i < N_GENE) sg[i] = 0.f; else sc[i - N_GENE] = 0.f;
        }
    }
}

// deg[j] = sum_b partial[b][j]; partial[b][j] := exclusive prefix over b;
// nrm[j] = rsqrt(max(deg,1)). Thread=bin; each b-iteration is coalesced.
__global__ void k_reduce(int* __restrict__ partial, int* __restrict__ deg,
                         float* __restrict__ nrm) {
    int j = blockIdx.x * blockDim.x + threadIdx.x;
    if (j < NBINS) {
        int s = 0;
        #pragma unroll
        for (int b0 = 0; b0 < NPART; b0 += 32) {
            int t[32];
            #pragma unroll
            for (int u = 0; u < 32; u++) t[u] = partial[(b0 + u) * NBINS + j];
            #pragma unroll
            for (int u = 0; u < 32; u++) { partial[(b0 + u) * NBINS + j] = s; s += t[u]; }
        }
        deg[j] = s;
        nrm[j] = rsqrtf(fmaxf((float)s, 1.0f));
    }
}

// Deterministic counting sort; each block recomputes the CSR-offset scan of its
// direction's degree segment in LDS, seeds cursors with offs+base_rank,
// places int2{src, norm_src}. grid=(NPART, 2). (verified R0 code)
__global__ __launch_bounds__(1024) void k_scatter(
        const int* __restrict__ g2c_src, const int* __restrict__ g2c_dst,
        const int* __restrict__ c2g_src, const int* __restrict__ c2g_dst,
        const int* __restrict__ deg, const int* __restrict__ partial,
        const float* __restrict__ nrm,
        int* __restrict__ offsC, int* __restrict__ offsG,
        int2* __restrict__ sortC, int2* __restrict__ sortG) {
    __shared__ int soffs[N_GENE + 1];
    __shared__ int scur[N_GENE];
    __shared__ int wsum[16];
    int T = threadIdx.x, blk = blockIdx.x, dir = blockIdx.y;
    const int* src  = dir ? c2g_src : g2c_src;
    const int* dst  = dir ? c2g_dst : g2c_dst;
    const int* dgs  = dir ? deg + S_G_IN : deg + S_C_IN;
    const float* nsv = dir ? nrm + S_C_OUT : nrm + S_G_OUT;
    int seg         = dir ? S_G_IN : S_C_IN;
    int nb          = dir ? N_GENE : N_CELL;
    int* goffs      = dir ? offsG : offsC;
    int2* sorted    = dir ? sortG : sortC;
    int per = (nb + 1023) >> 10;              // <=5
    int i0 = T * per, i1 = min(nb, i0 + per);
    int loc[5];
    int s = 0;
    for (int i = i0; i < i1; i++) { loc[i - i0] = s; s += dgs[i]; }
    int lane = T & 63, w = T >> 6;
    int t = s;
    #pragma unroll
    for (int off = 1; off < 64; off <<= 1) {
        int u = __shfl_up(t, off);
        if (lane >= off) t += u;
    }
    if (lane == 63) wsum[w] = t;
    __syncthreads();
    if (w == 0 && lane < 16) {
        int x = wsum[lane];
        #pragma unroll
        for (int off = 1; off < 16; off <<= 1) {
            int u = __shfl_up(x, off);
            if (lane >= off) x += u;
        }
        wsum[lane] = x;
    }
    __syncthreads();
    int wbase = w ? wsum[w - 1] : 0;
    int excl = wbase + t - s;
    for (int i = i0; i < i1; i++) soffs[i] = excl + loc[i - i0];
    if (T == 1023) soffs[nb] = excl + s;
    __syncthreads();
    if (blk == 0)
        for (int j = T; j <= nb; j += 1024) goffs[j] = soffs[j];
    const int* basep = partial + blk * NBINS + seg;
    for (int j = T; j < nb; j += 1024) scur[j] = soffs[j] + basep[j];
    __syncthreads();
    const int chunk = (NEDGE + NPART - 1) / NPART;
    int e0 = blk * chunk, e1 = min(NEDGE, e0 + chunk);
    for (int e = e0 + T; e < e1; e += 1024) {
        int d = dst[e], sv = src[e];
        float nv = nsv[sv];
        int pos = atomicAdd(&scur[d], 1);
        sorted[pos] = make_int2(sv, __float_as_int(nv));
    }
}

// Aggregation with paired-row 16B loads (verified), 8-deep steady-state loop.
__global__ __launch_bounds__(256) void k_agg(
        const unsigned short* __restrict__ gene_bf,
        const unsigned short* __restrict__ cell_bf,
        const int2* __restrict__ sortC, const int2* __restrict__ sortG,
        const int* __restrict__ offsC, const int* __restrict__ offsG,
        const float* __restrict__ nrm,
        unsigned short* __restrict__ aggC, unsigned short* __restrict__ aggG) {
    __shared__ int   sidx[4][64];
    __shared__ float snrm[4][64];
    __shared__ float pacc[4][256];
    int w = threadIdx.x >> 6, lane = threadIdx.x & 63;
    int half = lane >> 5, li = lane & 31;
    int B = blockIdx.x;
    bool isCell = B < N_CELL;

    int e0, e1;
    const unsigned short* emb;
    const int2* sorted;
    int node;
    if (isCell) {
        node = B;
        int f0 = offsC[node], f1 = offsC[node + 1];
        int ne = f1 - f0, nw = (ne + 3) >> 2;
        e0 = f0 + w * nw; e1 = min(f1, e0 + nw);
        emb = gene_bf; sorted = sortC;
    } else {
        node = (B - N_CELL) * 4 + w;
        if (node >= N_GENE) return;
        e0 = offsG[node]; e1 = offsG[node + 1];
        emb = cell_bf; sorted = sortG;
    }

    float acc[8];
    #pragma unroll
    for (int c = 0; c < 8; c++) acc[c] = 0.f;

    for (int base = e0; base < e1; base += 64) {
        int n = min(64, e1 - base);
        if (lane < n) {
            int2 pr = sorted[base + lane];
            sidx[w][lane] = pr.x;
            snrm[w][lane] = __int_as_float(pr.y);
        }
        // same-wave LDS write->read: program order, no barrier needed
        int i = 0;
        for (; 2 * i + 16 <= n; i += 8) {          // 8 loads in flight, 16 rows/iter
            ushort8v v[8];
            float nv[8];
            #pragma unroll
            for (int k = 0; k < 8; k++) {
                int jj = 2 * i + 2 * k + half;
                v[k] = *(const ushort8v*)&emb[sidx[w][jj] * D + li * 8];
                nv[k] = snrm[w][jj];
            }
            #pragma unroll
            for (int c = 0; c < 8; c++) {
                float s0 = 0.f;
                #pragma unroll
                for (int k = 0; k < 8; k++) s0 += bf2f(v[k][c]) * nv[k];
                acc[c] += s0;
            }
        }
        for (; 2 * i + 8 <= n; i += 4) {
            int j0 = 2 * i + half, j1 = 2 * i + 2 + half;
            int j2 = 2 * i + 4 + half, j3 = 2 * i + 6 + half;
            ushort8v v0 = *(const ushort8v*)&emb[sidx[w][j0] * D + li * 8];
            ushort8v v1 = *(const ushort8v*)&emb[sidx[w][j1] * D + li * 8];
            ushort8v v2 = *(const ushort8v*)&emb[sidx[w][j2] * D + li * 8];
            ushort8v v3 = *(const ushort8v*)&emb[sidx[w][j3] * D + li * 8];
            float n0 = snrm[w][j0], n1 = snrm[w][j1];
            float n2 = snrm[w][j2], n3 = snrm[w][j3];
            #pragma unroll
            for (int c = 0; c < 8; c++)
                acc[c] += bf2f(v0[c]) * n0 + bf2f(v1[c]) * n1 +
                          bf2f(v2[c]) * n2 + bf2f(v3[c]) * n3;
        }
        int npair = (n + 1) >> 1;
        for (; i < npair; i++) {
            int jj = 2 * i + half;
            bool ok = jj < n;
            int idx = ok ? sidx[w][jj] : sidx[w][0];
            float nv = ok ? snrm[w][jj] : 0.f;
            ushort8v v = *(const ushort8v*)&emb[idx * D + li * 8];
            #pragma unroll
            for (int c = 0; c < 8; c++) acc[c] += bf2f(v[c]) * nv;
        }
    }
    #pragma unroll
    for (int c = 0; c < 8; c++) acc[c] += __shfl_xor(acc[c], 32);

    if (isCell) {
        if (half == 0) {
            #pragma unroll
            for (int c = 0; c < 8; c++) pacc[w][li * 8 + c] = acc[c];
        }
        __syncthreads();
        int T = threadIdx.x;          // T = column
        float s2 = pacc[0][T] + pacc[1][T] + pacc[2][T] + pacc[3][T];
        aggC[node * D + T] = f2bf(s2 * nrm[S_C_IN + node]);
    } else {
        if (half == 0) {
            float ndv = nrm[S_G_IN + node];
            ushort8v o;
            #pragma unroll
            for (int c = 0; c < 8; c++) o[c] = f2bf(acc[c] * ndv);
            *(ushort8v*)&aggG[node * D + li * 8] = o;
        }
    }
}

// MFMA bf16 GEMM, N-split 4x for occupancy: wid = (tile, 64-col quadrant).
// H = relu(Agg @ W + b); Wp row-dot partials accumulated via f32 atomicAdd
// into pre-zeroed sg/sc.
__global__ __launch_bounds__(256) void k_gemm2(
        const unsigned short* __restrict__ aggC, const unsigned short* __restrict__ aggG,
        const unsigned short* __restrict__ wt1, const unsigned short* __restrict__ wt2,
        const float* __restrict__ b_g2c, const float* __restrict__ b_c2g,
        const float* __restrict__ Wp,
        float* __restrict__ hC, float* __restrict__ hG,
        float* __restrict__ sg, float* __restrict__ sc) {
    const int CT = (N_CELL + 15) / 16;   // 53
    const int GT = (N_GENE + 15) / 16;   // 298
    int wid = blockIdx.x * 4 + (threadIdx.x >> 6);
    if (wid >= (CT + GT) * 4) return;
    int tid = wid >> 2, nq = wid & 3;
    int n0 = nq * 64;
    bool isCell = tid < CT;
    int tile = isCell ? tid : tid - CT;
    int m0 = tile * 16;
    int M = isCell ? N_CELL : N_GENE;
    const unsigned short* A  = isCell ? aggC : aggG;
    const unsigned short* Wt = isCell ? wt1 : wt2;
    const float* bias = isCell ? b_g2c : b_c2g;
    const float* wp   = isCell ? Wp + D : Wp;
    float* H  = isCell ? hC : hG;
    float* sv = isCell ? sc : sg;
    int lane = threadIdx.x & 63;
    int l15 = lane & 15, quad = lane >> 4;
    int arow = m0 + l15;
    if (arow >= M) arow = M - 1;
    f32x4 acc[4];
    #pragma unroll
    for (int t = 0; t < 4; t++) acc[t] = (f32x4){0.f, 0.f, 0.f, 0.f};
    #pragma unroll
    for (int k0 = 0; k0 < D; k0 += 32) {
        short8 a = *(const short8*)&A[arow * D + k0 + quad * 8];
        #pragma unroll
        for (int t = 0; t < 4; t++) {
            short8 b = *(const short8*)&Wt[(n0 + t * 16 + l15) * D + k0 + quad * 8];
            acc[t] = __builtin_amdgcn_mfma_f32_16x16x32_bf16(a, b, acc[t], 0, 0, 0);
        }
    }
    float dot[4] = {0.f, 0.f, 0.f, 0.f};
    #pragma unroll
    for (int t = 0; t < 4; t++) {
        int col = n0 + t * 16 + l15;
        float bv = bias[col], wv = wp[col];
        #pragma unroll
        for (int r = 0; r < 4; r++) {
            int row = m0 + quad * 4 + r;
            float h = fmaxf(acc[t][r] + bv, 0.f);
            if (row < M) H[row * D + col] = h;
            dot[r] += h * wv;
        }
    }
    #pragma unroll
    for (int off = 1; off < 16; off <<= 1) {
        #pragma unroll
        for (int r = 0; r < 4; r++) dot[r] += __shfl_xor(dot[r], off);
    }
    if (l15 == 0) {
        #pragma unroll
        for (int r = 0; r < 4; r++) {
            int row = m0 + quad * 4 + r;
            if (row < M) atomicAdd(&sv[row], dot[r]);
        }
    }
}

__global__ void k_score(const int* __restrict__ dsrc, const int* __restrict__ ddst,
                        const float* __restrict__ sg, const float* __restrict__ sc,
                        const float* __restrict__ bp, float* __restrict__ out) {
    int i = blockIdx.x * blockDim.x + threadIdx.x;
    if (i < NEDGE) out[i] = sg[dsrc[i]] + sc[ddst[i]] + bp[0];
}

extern "C" void kernel_launch(void* const* d_in, const int* in_sizes, int n_in,
                              void* d_out, int out_size, void* d_ws, size_t ws_size,
                              hipStream_t stream) {
    const float* gene_emb = (const float*)d_in[0];
    const float* cell_emb = (const float*)d_in[1];
    const float* W_g2c    = (const float*)d_in[2];
    const float* b_g2c    = (const float*)d_in[3];
    const float* W_c2g    = (const float*)d_in[4];
    const float* b_c2g    = (const float*)d_in[5];
    const float* Wp       = (const float*)d_in[6];
    const float* bp       = (const float*)d_in[7];
    const int* g2c_src = (const int*)d_in[8];
    const int* g2c_dst = (const int*)d_in[9];
    const int* c2g_src = (const int*)d_in[10];
    const int* c2g_dst = (const int*)d_in[11];
    const int* dec_src = (const int*)d_in[12];
    const int* dec_dst = (const int*)d_in[13];

    int*   wsi = (int*)d_ws;
    float* wsf = (float*)d_ws;
    unsigned short* gene_bf = (unsigned short*)(wsi + A_GENE_BF);
    unsigned short* cell_bf = (unsigned short*)(wsi + A_CELL_BF);
    unsigned short* wt1     = (unsigned short*)(wsi + A_WT1_BF);
    unsigned short* wt2     = (unsigned short*)(wsi + A_WT2_BF);
    unsigned short* aggC    = (unsigned short*)(wsi + A_AGGC_BF);
    unsigned short* aggG    = (unsigned short*)(wsi + A_AGGG_BF);
    int2* sortC = (int2*)(wsi + A_SORT_C);
    int2* sortG = (int2*)(wsi + A_SORT_G);

    float* out = (float*)d_out;
    float* out_score = out;                      // [200000]
    float* out_hgene = out + NEDGE;              // [4762*256]
    float* out_hcell = out + NEDGE + N_GENE * D; // [847*256]

    // 1. segment-split hist (blocks 0..255) + bf16 cvt / W^T / sg,sc zero (256..319)
    k_pre<<<4 * NPART + 64, 1024, 0, stream>>>(g2c_src, g2c_dst, c2g_src, c2g_dst,
                                               gene_emb, cell_emb, W_g2c, W_c2g,
                                               wsi + A_PART, gene_bf, cell_bf, wt1, wt2,
                                               wsf + A_SG, wsf + A_SC);
    // 2. reduce partials -> deg, nrm; partial := per-block exclusive base ranks
    k_reduce<<<(NBINS + 255) / 256, 256, 0, stream>>>(wsi + A_PART, wsi + A_DEG,
                                                      wsf + A_NRM);
    // 3. counting sort (per-block LDS offset scan; publishes global offs)
    {
        dim3 grid(NPART, 2);
        k_scatter<<<grid, 1024, 0, stream>>>(g2c_src, g2c_dst, c2g_src, c2g_dst,
                                             wsi + A_DEG, wsi + A_PART, wsf + A_NRM,
                                             wsi + A_OFFS_C, wsi + A_OFFS_G,
                                             sortC, sortG);
    }
    // 4. aggregate: block-per-cell + wave-per-gene, paired-row 16B loads
    k_agg<<<N_CELL + (N_GENE + 3) / 4, 256, 0, stream>>>(
        gene_bf, cell_bf, sortC, sortG, wsi + A_OFFS_C, wsi + A_OFFS_G,
        wsf + A_NRM, aggC, aggG);
    // 5. MFMA GEMMs (N-split 4x) + bias + relu + atomic Wp row-dots
    {
        const int CT = (N_CELL + 15) / 16, GT = (N_GENE + 15) / 16;
        k_gemm2<<<CT + GT, 256, 0, stream>>>(aggC, aggG, wt1, wt2,
                                             b_g2c, b_c2g, Wp,
                                             out_hcell, out_hgene,
                                             wsf + A_SG, wsf + A_SC);
    }
    // 6. edge scores
    k_score<<<(NEDGE + 255) / 256, 256, 0, stream>>>(dec_src, dec_dst,
                                                     wsf + A_SG, wsf + A_SC, bp, out_score);
}